// Round 1
// baseline (3472.342 us; speedup 1.0000x reference)
//
#include <hip/hip_runtime.h>
#include <math.h>

constexpr int N = 50000;   // nodes
constexpr int E = 640000;  // edges
constexpr int D = 128;     // dim == hidden
constexpr int T = 100;     // targets per head

// ---------------- degree / per-edge coefficient ----------------

__global__ void deg_kernel(const float* __restrict__ ew, const int* __restrict__ dst,
                           float* __restrict__ deg) {
  int e = blockIdx.x * 256 + threadIdx.x;
  if (e < E) atomicAdd(&deg[dst[e]], ew[e]);
}

__global__ void dinv_kernel(const float* __restrict__ deg, float* __restrict__ dinv) {
  int i = blockIdx.x * 256 + threadIdx.x;
  if (i < N) {
    float d = fmaxf(deg[i] + 1.0f, 1e-12f);
    dinv[i] = 1.0f / sqrtf(d);   // full-precision sqrt, not v_rsq approx
  }
}

__global__ void coef_kernel(const float* __restrict__ ew, const int* __restrict__ src,
                            const int* __restrict__ dst, const float* __restrict__ dinv,
                            float* __restrict__ coef) {
  int e = blockIdx.x * 256 + threadIdx.x;
  if (e < E) coef[e] = dinv[src[e]] * ew[e] * dinv[dst[e]];
}

// ---------------- GEMM: out[N x 128] = A[N x 128] @ W[128 x 128] (+bias)(+relu) ----------------
// Block: 256 threads, 32 rows. K-chunked (KC=64): LDS = W-chunk 32KB + X-chunk 8KB = 40KB
// -> 4 blocks/CU. Each thread: 4 rows x 4 cols register tile.

__global__ __launch_bounds__(256) void gemm_kernel(
    const float* __restrict__ A, const float* __restrict__ W,
    const float* __restrict__ bias, float* __restrict__ out, int relu) {
  __shared__ float Wl[64 * D];   // W[kc..kc+64)[0..128)
  __shared__ float Xl[32 * 64];  // X[32 rows][kc..kc+64)
  const int tid = threadIdx.x;
  const int row0 = blockIdx.x * 32;
  const float4* __restrict__ W4 = (const float4*)W;
  const float4* __restrict__ A4 = (const float4*)A;
  float4* Wl4 = (float4*)Wl;
  float4* Xl4 = (float4*)Xl;

  const int cq = tid & 31;        // col quad: cols 4*cq..4*cq+3
  const int r0 = (tid >> 5) * 4;  // rows r0..r0+3 within tile
  float acc[4][4] = {};

  for (int kc = 0; kc < D; kc += 64) {
    // load W chunk: 64x128 floats = 2048 float4, coalesced
#pragma unroll
    for (int i = 0; i < 8; ++i) {
      int idx = tid + i * 256;
      int kk = idx >> 5, c4 = idx & 31;
      Wl4[idx] = W4[(kc + kk) * 32 + c4];
    }
    // load X chunk: 32x64 floats = 512 float4
#pragma unroll
    for (int i = 0; i < 2; ++i) {
      int idx = tid + i * 256;
      int r = idx >> 4, c4 = idx & 15;
      int gr = row0 + r; if (gr >= N) gr = N - 1;  // clamp reads, guard writes
      Xl4[idx] = A4[gr * 32 + (kc >> 2) + c4];
    }
    __syncthreads();
#pragma unroll 8
    for (int kk = 0; kk < 64; ++kk) {
      float4 wv = ((const float4*)Wl)[kk * 32 + cq];
#pragma unroll
      for (int j = 0; j < 4; ++j) {
        float x = Xl[(r0 + j) * 64 + kk];  // wave-broadcast (2 addrs/wave)
        acc[j][0] = fmaf(x, wv.x, acc[j][0]);
        acc[j][1] = fmaf(x, wv.y, acc[j][1]);
        acc[j][2] = fmaf(x, wv.z, acc[j][2]);
        acc[j][3] = fmaf(x, wv.w, acc[j][3]);
      }
    }
    __syncthreads();
  }

  float4 bv = make_float4(0.f, 0.f, 0.f, 0.f);
  if (bias) bv = ((const float4*)bias)[cq];
  float4* O4 = (float4*)out;
#pragma unroll
  for (int j = 0; j < 4; ++j) {
    int gr = row0 + r0 + j;
    if (gr < N) {
      float4 v;
      v.x = acc[j][0] + bv.x; v.y = acc[j][1] + bv.y;
      v.z = acc[j][2] + bv.z; v.w = acc[j][3] + bv.w;
      if (relu) {
        v.x = fmaxf(v.x, 0.f); v.y = fmaxf(v.y, 0.f);
        v.z = fmaxf(v.z, 0.f); v.w = fmaxf(v.w, 0.f);
      }
      O4[gr * 32 + cq] = v;
    }
  }
}

// ---------------- self-loop + bias init: out = dinv^2 * xw + b ----------------
// Must run before scatter adds edge contributions. Exactly N*32 float4s.

__global__ void selfloop_init_kernel(const float* __restrict__ xw, const float* __restrict__ dinv,
                                     const float* __restrict__ bias, float* __restrict__ out) {
  int i = blockIdx.x * 256 + threadIdx.x;  // float4 index
  int row = i >> 5;
  float dv = dinv[row];
  float s = dv * dv;
  float4 v = ((const float4*)xw)[i];
  float4 b = ((const float4*)bias)[i & 31];
  float4 o;
  o.x = fmaf(s, v.x, b.x);
  o.y = fmaf(s, v.y, b.y);
  o.z = fmaf(s, v.z, b.z);
  o.w = fmaf(s, v.w, b.w);
  ((float4*)out)[i] = o;
}

// ---------------- edge scatter: out[dst] += coef * xw[src] (atomics) ----------------
// 32 threads per edge, each thread 4 floats (float4 load, 4 scalar atomics).

__global__ __launch_bounds__(256) void scatter_kernel(
    const float* __restrict__ xw, const float* __restrict__ coef,
    const int* __restrict__ src, const int* __restrict__ dst,
    float* __restrict__ out) {
  int t = blockIdx.x * 256 + threadIdx.x;
  int e = t >> 5;
  if (e >= E) return;
  int lane = t & 31;
  float c = coef[e];
  int s = src[e], d = dst[e];
  float4 v = ((const float4*)xw)[s * 32 + lane];
  float* o = out + d * D + lane * 4;
  atomicAdd(o + 0, c * v.x);
  atomicAdd(o + 1, c * v.y);
  atomicAdd(o + 2, c * v.z);
  atomicAdd(o + 3, c * v.w);
}

// ---------------- relu in place ----------------

__global__ void relu_kernel(float* __restrict__ h) {
  int i = blockIdx.x * 256 + threadIdx.x;  // float4 index, exact grid
  float4 v = ((float4*)h)[i];
  v.x = fmaxf(v.x, 0.f); v.y = fmaxf(v.y, 0.f);
  v.z = fmaxf(v.z, 0.f); v.w = fmaxf(v.w, 0.f);
  ((float4*)h)[i] = v;
}

// ---------------- heads: out[t] = dot(h[idx], w) + b ----------------
// One wave (64 lanes) per output; shuffle reduce.

__global__ void heads_kernel(const float* __restrict__ h,
                             const int* __restrict__ ace_idx, const int* __restrict__ h2_idx,
                             const float* __restrict__ Wace, const float* __restrict__ bace,
                             const float* __restrict__ Wh2, const float* __restrict__ bh2,
                             float* __restrict__ out) {
  int t = blockIdx.x;       // 0..2T-1
  int lane = threadIdx.x;   // 0..63
  int node; const float* w; float b;
  if (t < T) { node = ace_idx[t];     w = Wace; b = bace[0]; }
  else       { node = h2_idx[t - T];  w = Wh2;  b = bh2[0]; }
  const float* hr = h + node * D;
  float v = hr[lane] * w[lane] + hr[lane + 64] * w[lane + 64];
#pragma unroll
  for (int off = 32; off; off >>= 1) v += __shfl_down(v, off, 64);
  if (lane == 0) out[t] = v + b;
}

// ---------------- launch ----------------

extern "C" void kernel_launch(void* const* d_in, const int* in_sizes, int n_in,
                              void* d_out, int out_size, void* d_ws, size_t ws_size,
                              hipStream_t stream) {
  const float* x    = (const float*)d_in[0];
  const int*   ei   = (const int*)d_in[1];
  const float* ew   = (const float*)d_in[2];
  const int*   ace  = (const int*)d_in[3];
  const int*   h2   = (const int*)d_in[4];
  const float* W1 = (const float*)d_in[5];  const float* b1 = (const float*)d_in[6];
  const float* W2 = (const float*)d_in[7];  const float* b2 = (const float*)d_in[8];
  const float* W3 = (const float*)d_in[9];  const float* b3 = (const float*)d_in[10];
  const float* Wh = (const float*)d_in[11]; const float* bh = (const float*)d_in[12];
  const float* Wace = (const float*)d_in[13]; const float* bace = (const float*)d_in[14];
  const float* Wh2  = (const float*)d_in[15]; const float* bh2  = (const float*)d_in[16];
  const int* src = ei;          // edge_index row 0
  const int* dst = ei + E;      // edge_index row 1

  // workspace layout (all fp32, offsets keep 16B alignment)
  float* f    = (float*)d_ws;
  float* deg  = f;                         // N
  float* dinv = deg + N;                   // N
  float* coef = dinv + N;                  // E
  float* xw   = coef + E;                  // N*D
  float* hA   = xw + (size_t)N * D;        // N*D
  float* hB   = hA + (size_t)N * D;        // N*D  (total ~80 MB)

  hipMemsetAsync(deg, 0, N * sizeof(float), stream);
  deg_kernel<<<(E + 255) / 256, 256, 0, stream>>>(ew, dst, deg);
  dinv_kernel<<<(N + 255) / 256, 256, 0, stream>>>(deg, dinv);
  coef_kernel<<<(E + 255) / 256, 256, 0, stream>>>(ew, src, dst, dinv, coef);

  const int GG = (N + 31) / 32;        // 1563
  const int EW = E * 32 / 256;         // 80000 (exact)
  const int NW = N * 32 / 256;         // 6250  (exact, N*D/4 float4s / 256)

  // layer 1: x -> hA
  gemm_kernel<<<GG, 256, 0, stream>>>(x, W1, nullptr, xw, 0);
  selfloop_init_kernel<<<NW, 256, 0, stream>>>(xw, dinv, b1, hA);
  scatter_kernel<<<EW, 256, 0, stream>>>(xw, coef, src, dst, hA);
  relu_kernel<<<NW, 256, 0, stream>>>(hA);
  // layer 2: hA -> hB
  gemm_kernel<<<GG, 256, 0, stream>>>(hA, W2, nullptr, xw, 0);
  selfloop_init_kernel<<<NW, 256, 0, stream>>>(xw, dinv, b2, hB);
  scatter_kernel<<<EW, 256, 0, stream>>>(xw, coef, src, dst, hB);
  relu_kernel<<<NW, 256, 0, stream>>>(hB);
  // layer 3: hB -> hA
  gemm_kernel<<<GG, 256, 0, stream>>>(hB, W3, nullptr, xw, 0);
  selfloop_init_kernel<<<NW, 256, 0, stream>>>(xw, dinv, b3, hA);
  scatter_kernel<<<EW, 256, 0, stream>>>(xw, coef, src, dst, hA);
  relu_kernel<<<NW, 256, 0, stream>>>(hA);
  // dense head layer: hB = relu(hA @ Wh + bh)
  gemm_kernel<<<GG, 256, 0, stream>>>(hA, Wh, bh, hB, 1);
  // heads -> d_out[0..2T)
  heads_kernel<<<2 * T, 64, 0, stream>>>(hB, ace, h2, Wace, bace, Wh2, bh2, (float*)d_out);
}

// Round 2
// 604.145 us; speedup vs baseline: 5.7475x; 5.7475x over previous
//
#include <hip/hip_runtime.h>
#include <math.h>

constexpr int N = 50000;   // nodes
constexpr int E = 640000;  // edges
constexpr int D = 128;     // dim == hidden
constexpr int T = 100;     // targets per head

// ---------------- degree (float) + count (int) histogram ----------------

__global__ void deg_count_kernel(const float* __restrict__ ew, const int* __restrict__ dst,
                                 float* __restrict__ deg, int* __restrict__ counts) {
  int e = blockIdx.x * 256 + threadIdx.x;
  if (e < E) {
    int d = dst[e];
    atomicAdd(&deg[d], ew[e]);
    atomicAdd(&counts[d], 1);
  }
}

__global__ void dinv_kernel(const float* __restrict__ deg, float* __restrict__ dinv) {
  int i = blockIdx.x * 256 + threadIdx.x;
  if (i < N) {
    float d = fmaxf(deg[i] + 1.0f, 1e-12f);
    dinv[i] = 1.0f / sqrtf(d);
  }
}

__global__ void coef_kernel(const float* __restrict__ ew, const int* __restrict__ src,
                            const int* __restrict__ dst, const float* __restrict__ dinv,
                            float* __restrict__ coef) {
  int e = blockIdx.x * 256 + threadIdx.x;
  if (e < E) coef[e] = dinv[src[e]] * ew[e] * dinv[dst[e]];
}

// ---------------- single-workgroup exclusive scan over counts[N] ----------------
// 1024 threads, each owns a 49-element chunk; Hillis-Steele over partials in LDS.

__global__ __launch_bounds__(1024) void scan_kernel(const int* __restrict__ counts,
                                                    int* __restrict__ offs,
                                                    int* __restrict__ cursor) {
  constexpr int CHUNK = (N + 1023) / 1024;  // 49
  __shared__ int part[1024];
  int t = threadIdx.x;
  int base = t * CHUNK;
  int sum = 0;
#pragma unroll
  for (int i = 0; i < CHUNK; ++i) {
    int idx = base + i;
    if (idx < N) sum += counts[idx];
  }
  part[t] = sum;
  __syncthreads();
  for (int off = 1; off < 1024; off <<= 1) {
    int v = (t >= off) ? part[t - off] : 0;
    __syncthreads();
    part[t] += v;
    __syncthreads();
  }
  int run = part[t] - sum;  // exclusive prefix of this chunk
#pragma unroll
  for (int i = 0; i < CHUNK; ++i) {
    int idx = base + i;
    if (idx < N) {
      offs[idx] = run;
      cursor[idx] = run;
      run += counts[idx];
    }
  }
  if (t == 1023) offs[N] = run;  // == E
}

// ---------------- CSR fill: packed (src, coef) sorted by dst ----------------

__global__ void fill_kernel(const int* __restrict__ src, const int* __restrict__ dst,
                            const float* __restrict__ coef, int* __restrict__ cursor,
                            int2* __restrict__ csr) {
  int e = blockIdx.x * 256 + threadIdx.x;
  if (e < E) {
    int pos = atomicAdd(&cursor[dst[e]], 1);
    csr[pos] = make_int2(src[e], __float_as_int(coef[e]));
  }
}

// ---------------- GEMM: out[N x 128] = A[N x 128] @ W[128 x 128] (+bias)(+relu) ----------------

__global__ __launch_bounds__(256) void gemm_kernel(
    const float* __restrict__ A, const float* __restrict__ W,
    const float* __restrict__ bias, float* __restrict__ out, int relu) {
  __shared__ float Wl[64 * D];   // W[kc..kc+64)[0..128)
  __shared__ float Xl[32 * 64];  // X[32 rows][kc..kc+64)
  const int tid = threadIdx.x;
  const int row0 = blockIdx.x * 32;
  const float4* __restrict__ W4 = (const float4*)W;
  const float4* __restrict__ A4 = (const float4*)A;
  float4* Wl4 = (float4*)Wl;
  float4* Xl4 = (float4*)Xl;

  const int cq = tid & 31;        // col quad: cols 4*cq..4*cq+3
  const int r0 = (tid >> 5) * 4;  // rows r0..r0+3 within tile
  float acc[4][4] = {};

  for (int kc = 0; kc < D; kc += 64) {
#pragma unroll
    for (int i = 0; i < 8; ++i) {
      int idx = tid + i * 256;
      int kk = idx >> 5, c4 = idx & 31;
      Wl4[idx] = W4[(kc + kk) * 32 + c4];
    }
#pragma unroll
    for (int i = 0; i < 2; ++i) {
      int idx = tid + i * 256;
      int r = idx >> 4, c4 = idx & 15;
      int gr = row0 + r; if (gr >= N) gr = N - 1;
      Xl4[idx] = A4[gr * 32 + (kc >> 2) + c4];
    }
    __syncthreads();
#pragma unroll 8
    for (int kk = 0; kk < 64; ++kk) {
      float4 wv = ((const float4*)Wl)[kk * 32 + cq];
#pragma unroll
      for (int j = 0; j < 4; ++j) {
        float x = Xl[(r0 + j) * 64 + kk];
        acc[j][0] = fmaf(x, wv.x, acc[j][0]);
        acc[j][1] = fmaf(x, wv.y, acc[j][1]);
        acc[j][2] = fmaf(x, wv.z, acc[j][2]);
        acc[j][3] = fmaf(x, wv.w, acc[j][3]);
      }
    }
    __syncthreads();
  }

  float4 bv = make_float4(0.f, 0.f, 0.f, 0.f);
  if (bias) bv = ((const float4*)bias)[cq];
  float4* O4 = (float4*)out;
#pragma unroll
  for (int j = 0; j < 4; ++j) {
    int gr = row0 + r0 + j;
    if (gr < N) {
      float4 v;
      v.x = acc[j][0] + bv.x; v.y = acc[j][1] + bv.y;
      v.z = acc[j][2] + bv.z; v.w = acc[j][3] + bv.w;
      if (relu) {
        v.x = fmaxf(v.x, 0.f); v.y = fmaxf(v.y, 0.f);
        v.z = fmaxf(v.z, 0.f); v.w = fmaxf(v.w, 0.f);
      }
      O4[gr * 32 + cq] = v;
    }
  }
}

// ---------------- pull aggregation: out[n] = relu(dinv[n]^2*xw[n] + b + sum_e coef*xw[src]) ----
// 32 lanes per node, one float4 per lane. 2-edge unrolled gather loop. No atomics.

__global__ __launch_bounds__(256) void agg_kernel(
    const float* __restrict__ xw, const int2* __restrict__ csr,
    const int* __restrict__ offs, const float* __restrict__ dinv,
    const float* __restrict__ bias, float* __restrict__ out) {
  int g = (blockIdx.x * 256 + threadIdx.x) >> 5;  // node (N divisible by 8 per block)
  if (g >= N) return;
  int lane = threadIdx.x & 31;
  const float4* __restrict__ xw4 = (const float4*)xw;

  float dv = dinv[g];
  float s = dv * dv;
  float4 xv = xw4[g * 32 + lane];
  float4 bv = ((const float4*)bias)[lane];
  float4 acc;
  acc.x = fmaf(s, xv.x, bv.x);
  acc.y = fmaf(s, xv.y, bv.y);
  acc.z = fmaf(s, xv.z, bv.z);
  acc.w = fmaf(s, xv.w, bv.w);

  int e = offs[g], e1 = offs[g + 1];
  for (; e + 2 <= e1; e += 2) {
    int2 p0 = csr[e], p1 = csr[e + 1];
    float c0 = __int_as_float(p0.y), c1 = __int_as_float(p1.y);
    float4 v0 = xw4[p0.x * 32 + lane];
    float4 v1 = xw4[p1.x * 32 + lane];
    acc.x = fmaf(c0, v0.x, acc.x); acc.y = fmaf(c0, v0.y, acc.y);
    acc.z = fmaf(c0, v0.z, acc.z); acc.w = fmaf(c0, v0.w, acc.w);
    acc.x = fmaf(c1, v1.x, acc.x); acc.y = fmaf(c1, v1.y, acc.y);
    acc.z = fmaf(c1, v1.z, acc.z); acc.w = fmaf(c1, v1.w, acc.w);
  }
  if (e < e1) {
    int2 p = csr[e];
    float c = __int_as_float(p.y);
    float4 v = xw4[p.x * 32 + lane];
    acc.x = fmaf(c, v.x, acc.x); acc.y = fmaf(c, v.y, acc.y);
    acc.z = fmaf(c, v.z, acc.z); acc.w = fmaf(c, v.w, acc.w);
  }
  acc.x = fmaxf(acc.x, 0.f); acc.y = fmaxf(acc.y, 0.f);
  acc.z = fmaxf(acc.z, 0.f); acc.w = fmaxf(acc.w, 0.f);
  ((float4*)out)[g * 32 + lane] = acc;
}

// ---------------- heads: out[t] = dot(h[idx], w) + b ----------------

__global__ void heads_kernel(const float* __restrict__ h,
                             const int* __restrict__ ace_idx, const int* __restrict__ h2_idx,
                             const float* __restrict__ Wace, const float* __restrict__ bace,
                             const float* __restrict__ Wh2, const float* __restrict__ bh2,
                             float* __restrict__ out) {
  int t = blockIdx.x;       // 0..2T-1
  int lane = threadIdx.x;   // 0..63
  int node; const float* w; float b;
  if (t < T) { node = ace_idx[t];     w = Wace; b = bace[0]; }
  else       { node = h2_idx[t - T];  w = Wh2;  b = bh2[0]; }
  const float* hr = h + node * D;
  float v = hr[lane] * w[lane] + hr[lane + 64] * w[lane + 64];
#pragma unroll
  for (int off = 32; off; off >>= 1) v += __shfl_down(v, off, 64);
  if (lane == 0) out[t] = v + b;
}

// ---------------- launch ----------------

extern "C" void kernel_launch(void* const* d_in, const int* in_sizes, int n_in,
                              void* d_out, int out_size, void* d_ws, size_t ws_size,
                              hipStream_t stream) {
  const float* x    = (const float*)d_in[0];
  const int*   ei   = (const int*)d_in[1];
  const float* ew   = (const float*)d_in[2];
  const int*   ace  = (const int*)d_in[3];
  const int*   h2   = (const int*)d_in[4];
  const float* W1 = (const float*)d_in[5];  const float* b1 = (const float*)d_in[6];
  const float* W2 = (const float*)d_in[7];  const float* b2 = (const float*)d_in[8];
  const float* W3 = (const float*)d_in[9];  const float* b3 = (const float*)d_in[10];
  const float* Wh = (const float*)d_in[11]; const float* bh = (const float*)d_in[12];
  const float* Wace = (const float*)d_in[13]; const float* bace = (const float*)d_in[14];
  const float* Wh2  = (const float*)d_in[15]; const float* bh2  = (const float*)d_in[16];
  const int* src = ei;          // edge_index row 0
  const int* dst = ei + E;      // edge_index row 1

  // workspace layout (16B-aligned blocks)
  char* w = (char*)d_ws;
  float* deg    = (float*)w;              w += N * 4;            // zeroed (with counts)
  int*   counts = (int*)w;                w += N * 4;            // zeroed
  float* dinv   = (float*)w;              w += N * 4;
  int*   offs   = (int*)w;                w += (N + 4) * 4;      // N+1 used, padded
  int*   cursor = (int*)w;                w += N * 4;
  float* coef   = (float*)w;              w += (size_t)E * 4;
  int2*  csr    = (int2*)w;               w += (size_t)E * 8;
  float* xw     = (float*)w;              w += (size_t)N * D * 4;
  float* hA     = (float*)w;              w += (size_t)N * D * 4;
  float* hB     = (float*)w;              w += (size_t)N * D * 4;  // total ~86 MB

  // ---- graph-structure build (once per call) ----
  hipMemsetAsync(deg, 0, 2 * N * sizeof(float), stream);  // deg + counts adjacent
  deg_count_kernel<<<(E + 255) / 256, 256, 0, stream>>>(ew, dst, deg, counts);
  dinv_kernel<<<(N + 255) / 256, 256, 0, stream>>>(deg, dinv);
  coef_kernel<<<(E + 255) / 256, 256, 0, stream>>>(ew, src, dst, dinv, coef);
  scan_kernel<<<1, 1024, 0, stream>>>(counts, offs, cursor);
  fill_kernel<<<(E + 255) / 256, 256, 0, stream>>>(src, dst, coef, cursor, csr);

  const int GG = (N + 31) / 32;   // 1563 gemm blocks
  const int AG = N * 32 / 256;    // 6250 agg blocks (exact)

  // layer 1: x -> hA
  gemm_kernel<<<GG, 256, 0, stream>>>(x, W1, nullptr, xw, 0);
  agg_kernel<<<AG, 256, 0, stream>>>(xw, csr, offs, dinv, b1, hA);
  // layer 2: hA -> hB
  gemm_kernel<<<GG, 256, 0, stream>>>(hA, W2, nullptr, xw, 0);
  agg_kernel<<<AG, 256, 0, stream>>>(xw, csr, offs, dinv, b2, hB);
  // layer 3: hB -> hA
  gemm_kernel<<<GG, 256, 0, stream>>>(hB, W3, nullptr, xw, 0);
  agg_kernel<<<AG, 256, 0, stream>>>(xw, csr, offs, dinv, b3, hA);
  // dense head layer: hB = relu(hA @ Wh + bh)
  gemm_kernel<<<GG, 256, 0, stream>>>(hA, Wh, bh, hB, 1);
  // heads -> d_out[0..2T)
  heads_kernel<<<2 * T, 64, 0, stream>>>(hB, ace, h2, Wace, bace, Wh2, bh2, (float*)d_out);
}

// Round 3
// 492.647 us; speedup vs baseline: 7.0483x; 1.2263x over previous
//
#include <hip/hip_runtime.h>
#include <math.h>

constexpr int N = 50000;   // nodes
constexpr int E = 640000;  // edges
constexpr int D = 128;     // dim == hidden
constexpr int T = 100;     // targets per head
constexpr int NB = (N + 255) / 256;  // 196 scan blocks

// ---------------- degree (float) + count (int) histogram ----------------

__global__ void deg_count_kernel(const float* __restrict__ ew, const int* __restrict__ dst,
                                 float* __restrict__ deg, int* __restrict__ counts) {
  int e = blockIdx.x * 256 + threadIdx.x;
  if (e < E) {
    int d = dst[e];
    atomicAdd(&deg[d], ew[e]);
    atomicAdd(&counts[d], 1);
  }
}

__global__ void dinv_kernel(const float* __restrict__ deg, float* __restrict__ dinv) {
  int i = blockIdx.x * 256 + threadIdx.x;
  if (i < N) {
    float d = fmaxf(deg[i] + 1.0f, 1e-12f);
    dinv[i] = 1.0f / sqrtf(d);
  }
}

__global__ void coef_kernel(const float* __restrict__ ew, const int* __restrict__ src,
                            const int* __restrict__ dst, const float* __restrict__ dinv,
                            float* __restrict__ coef) {
  int e = blockIdx.x * 256 + threadIdx.x;
  if (e < E) coef[e] = dinv[src[e]] * ew[e] * dinv[dst[e]];
}

// ---------------- parallel 3-phase exclusive scan over counts[N] ----------------

__global__ __launch_bounds__(256) void scan_reduce_kernel(const int* __restrict__ counts,
                                                          int* __restrict__ bsum) {
  __shared__ int part[256];
  int t = threadIdx.x;
  int i = blockIdx.x * 256 + t;
  part[t] = (i < N) ? counts[i] : 0;
  __syncthreads();
#pragma unroll
  for (int off = 128; off; off >>= 1) {
    if (t < off) part[t] += part[t + off];
    __syncthreads();
  }
  if (t == 0) bsum[blockIdx.x] = part[0];
}

__global__ __launch_bounds__(256) void scan_bsum_kernel(int* __restrict__ bsum) {
  __shared__ int part[256];
  int t = threadIdx.x;
  int v = (t < NB) ? bsum[t] : 0;
  part[t] = v;
  __syncthreads();
#pragma unroll
  for (int off = 1; off < 256; off <<= 1) {
    int u = (t >= off) ? part[t - off] : 0;
    __syncthreads();
    part[t] += u;
    __syncthreads();
  }
  if (t < NB) bsum[t] = part[t] - v;  // exclusive
}

__global__ __launch_bounds__(256) void scan_apply_kernel(const int* __restrict__ counts,
                                                         const int* __restrict__ bsum,
                                                         int* __restrict__ offs,
                                                         int* __restrict__ cursor) {
  __shared__ int part[256];
  int t = threadIdx.x;
  int i = blockIdx.x * 256 + t;
  int c = (i < N) ? counts[i] : 0;
  part[t] = c;
  __syncthreads();
#pragma unroll
  for (int off = 1; off < 256; off <<= 1) {
    int u = (t >= off) ? part[t - off] : 0;
    __syncthreads();
    part[t] += u;
    __syncthreads();
  }
  if (i < N) {
    int o = bsum[blockIdx.x] + part[t] - c;  // exclusive
    offs[i] = o;
    cursor[i] = o;
  }
  if (i == 0) offs[N] = E;  // total count is exactly E
}

// ---------------- CSR fill: packed (src, coef) sorted by dst ----------------

__global__ void fill_kernel(const int* __restrict__ src, const int* __restrict__ dst,
                            const float* __restrict__ coef, int* __restrict__ cursor,
                            int2* __restrict__ csr) {
  int e = blockIdx.x * 256 + threadIdx.x;
  if (e < E) {
    int pos = atomicAdd(&cursor[dst[e]], 1);
    csr[pos] = make_int2(src[e], __float_as_int(coef[e]));
  }
}

// ---------------- GEMM: out[N x 128] = A[N x 128] @ W[128 x 128] (+bias)(+relu) ----------------
// 256 threads, 32 rows/block, K-chunked by 64. Inner loop unrolled by 4 k-steps:
// X read as float4 from LDS (contiguous in k) -> 8 ds_read_b128 per 64 FMA (VALU-bound).

__global__ __launch_bounds__(256) void gemm_kernel(
    const float* __restrict__ A, const float* __restrict__ W,
    const float* __restrict__ bias, float* __restrict__ out, int relu) {
  __shared__ float Wl[64 * D];   // W[kc..kc+64)[0..128)
  __shared__ float Xl[32 * 64];  // X[32 rows][kc..kc+64)
  const int tid = threadIdx.x;
  const int row0 = blockIdx.x * 32;
  const float4* __restrict__ W4 = (const float4*)W;
  const float4* __restrict__ A4 = (const float4*)A;
  float4* Wl4 = (float4*)Wl;
  float4* Xl4 = (float4*)Xl;

  const int cq = tid & 31;        // col quad: cols 4*cq..4*cq+3
  const int r0 = (tid >> 5) * 4;  // rows r0..r0+3 within tile
  float acc[4][4] = {};

  for (int kc = 0; kc < D; kc += 64) {
#pragma unroll
    for (int i = 0; i < 8; ++i) {
      int idx = tid + i * 256;
      int kk = idx >> 5, c4 = idx & 31;
      Wl4[idx] = W4[(kc + kk) * 32 + c4];
    }
#pragma unroll
    for (int i = 0; i < 2; ++i) {
      int idx = tid + i * 256;
      int r = idx >> 4, c4 = idx & 15;
      int gr = row0 + r; if (gr >= N) gr = N - 1;
      Xl4[idx] = A4[gr * 32 + (kc >> 2) + c4];
    }
    __syncthreads();
#pragma unroll
    for (int kk = 0; kk < 64; kk += 4) {
      float4 wv0 = ((const float4*)Wl)[(kk + 0) * 32 + cq];
      float4 wv1 = ((const float4*)Wl)[(kk + 1) * 32 + cq];
      float4 wv2 = ((const float4*)Wl)[(kk + 2) * 32 + cq];
      float4 wv3 = ((const float4*)Wl)[(kk + 3) * 32 + cq];
#pragma unroll
      for (int j = 0; j < 4; ++j) {
        float4 xv = *(const float4*)&Xl[(r0 + j) * 64 + kk];
        acc[j][0] = fmaf(xv.x, wv0.x, acc[j][0]);
        acc[j][1] = fmaf(xv.x, wv0.y, acc[j][1]);
        acc[j][2] = fmaf(xv.x, wv0.z, acc[j][2]);
        acc[j][3] = fmaf(xv.x, wv0.w, acc[j][3]);
        acc[j][0] = fmaf(xv.y, wv1.x, acc[j][0]);
        acc[j][1] = fmaf(xv.y, wv1.y, acc[j][1]);
        acc[j][2] = fmaf(xv.y, wv1.z, acc[j][2]);
        acc[j][3] = fmaf(xv.y, wv1.w, acc[j][3]);
        acc[j][0] = fmaf(xv.z, wv2.x, acc[j][0]);
        acc[j][1] = fmaf(xv.z, wv2.y, acc[j][1]);
        acc[j][2] = fmaf(xv.z, wv2.z, acc[j][2]);
        acc[j][3] = fmaf(xv.z, wv2.w, acc[j][3]);
        acc[j][0] = fmaf(xv.w, wv3.x, acc[j][0]);
        acc[j][1] = fmaf(xv.w, wv3.y, acc[j][1]);
        acc[j][2] = fmaf(xv.w, wv3.z, acc[j][2]);
        acc[j][3] = fmaf(xv.w, wv3.w, acc[j][3]);
      }
    }
    __syncthreads();
  }

  float4 bv = make_float4(0.f, 0.f, 0.f, 0.f);
  if (bias) bv = ((const float4*)bias)[cq];
  float4* O4 = (float4*)out;
#pragma unroll
  for (int j = 0; j < 4; ++j) {
    int gr = row0 + r0 + j;
    if (gr < N) {
      float4 v;
      v.x = acc[j][0] + bv.x; v.y = acc[j][1] + bv.y;
      v.z = acc[j][2] + bv.z; v.w = acc[j][3] + bv.w;
      if (relu) {
        v.x = fmaxf(v.x, 0.f); v.y = fmaxf(v.y, 0.f);
        v.z = fmaxf(v.z, 0.f); v.w = fmaxf(v.w, 0.f);
      }
      O4[gr * 32 + cq] = v;
    }
  }
}

// ---------------- pull aggregation: out[n] = relu(dinv[n]^2*xw[n] + b + sum_e coef*xw[src]) ----

__global__ __launch_bounds__(256) void agg_kernel(
    const float* __restrict__ xw, const int2* __restrict__ csr,
    const int* __restrict__ offs, const float* __restrict__ dinv,
    const float* __restrict__ bias, float* __restrict__ out) {
  int g = (blockIdx.x * 256 + threadIdx.x) >> 5;  // node
  if (g >= N) return;
  int lane = threadIdx.x & 31;
  const float4* __restrict__ xw4 = (const float4*)xw;

  float dv = dinv[g];
  float s = dv * dv;
  float4 xv = xw4[g * 32 + lane];
  float4 bv = ((const float4*)bias)[lane];
  float4 acc;
  acc.x = fmaf(s, xv.x, bv.x);
  acc.y = fmaf(s, xv.y, bv.y);
  acc.z = fmaf(s, xv.z, bv.z);
  acc.w = fmaf(s, xv.w, bv.w);

  int e = offs[g], e1 = offs[g + 1];
  for (; e + 2 <= e1; e += 2) {
    int2 p0 = csr[e], p1 = csr[e + 1];
    float c0 = __int_as_float(p0.y), c1 = __int_as_float(p1.y);
    float4 v0 = xw4[p0.x * 32 + lane];
    float4 v1 = xw4[p1.x * 32 + lane];
    acc.x = fmaf(c0, v0.x, acc.x); acc.y = fmaf(c0, v0.y, acc.y);
    acc.z = fmaf(c0, v0.z, acc.z); acc.w = fmaf(c0, v0.w, acc.w);
    acc.x = fmaf(c1, v1.x, acc.x); acc.y = fmaf(c1, v1.y, acc.y);
    acc.z = fmaf(c1, v1.z, acc.z); acc.w = fmaf(c1, v1.w, acc.w);
  }
  if (e < e1) {
    int2 p = csr[e];
    float c = __int_as_float(p.y);
    float4 v = xw4[p.x * 32 + lane];
    acc.x = fmaf(c, v.x, acc.x); acc.y = fmaf(c, v.y, acc.y);
    acc.z = fmaf(c, v.z, acc.z); acc.w = fmaf(c, v.w, acc.w);
  }
  acc.x = fmaxf(acc.x, 0.f); acc.y = fmaxf(acc.y, 0.f);
  acc.z = fmaxf(acc.z, 0.f); acc.w = fmaxf(acc.w, 0.f);
  ((float4*)out)[g * 32 + lane] = acc;
}

// ---------------- heads: out[t] = dot(h[idx], w) + b ----------------

__global__ void heads_kernel(const float* __restrict__ h,
                             const int* __restrict__ ace_idx, const int* __restrict__ h2_idx,
                             const float* __restrict__ Wace, const float* __restrict__ bace,
                             const float* __restrict__ Wh2, const float* __restrict__ bh2,
                             float* __restrict__ out) {
  int t = blockIdx.x;       // 0..2T-1
  int lane = threadIdx.x;   // 0..63
  int node; const float* w; float b;
  if (t < T) { node = ace_idx[t];     w = Wace; b = bace[0]; }
  else       { node = h2_idx[t - T];  w = Wh2;  b = bh2[0]; }
  const float* hr = h + node * D;
  float v = hr[lane] * w[lane] + hr[lane + 64] * w[lane + 64];
#pragma unroll
  for (int off = 32; off; off >>= 1) v += __shfl_down(v, off, 64);
  if (lane == 0) out[t] = v + b;
}

// ---------------- launch ----------------

extern "C" void kernel_launch(void* const* d_in, const int* in_sizes, int n_in,
                              void* d_out, int out_size, void* d_ws, size_t ws_size,
                              hipStream_t stream) {
  const float* x    = (const float*)d_in[0];
  const int*   ei   = (const int*)d_in[1];
  const float* ew   = (const float*)d_in[2];
  const int*   ace  = (const int*)d_in[3];
  const int*   h2   = (const int*)d_in[4];
  const float* W1 = (const float*)d_in[5];  const float* b1 = (const float*)d_in[6];
  const float* W2 = (const float*)d_in[7];  const float* b2 = (const float*)d_in[8];
  const float* W3 = (const float*)d_in[9];  const float* b3 = (const float*)d_in[10];
  const float* Wh = (const float*)d_in[11]; const float* bh = (const float*)d_in[12];
  const float* Wace = (const float*)d_in[13]; const float* bace = (const float*)d_in[14];
  const float* Wh2  = (const float*)d_in[15]; const float* bh2  = (const float*)d_in[16];
  const int* src = ei;          // edge_index row 0
  const int* dst = ei + E;      // edge_index row 1

  // workspace layout (16B-aligned blocks)
  char* w = (char*)d_ws;
  float* deg    = (float*)w;              w += N * 4;            // zeroed (with counts)
  int*   counts = (int*)w;                w += N * 4;            // zeroed
  float* dinv   = (float*)w;              w += N * 4;
  int*   offs   = (int*)w;                w += (N + 4) * 4;      // N+1 used, padded
  int*   cursor = (int*)w;                w += N * 4;
  int*   bsum   = (int*)w;                w += 256 * 4;
  float* coef   = (float*)w;              w += (size_t)E * 4;
  int2*  csr    = (int2*)w;               w += (size_t)E * 8;
  float* xw     = (float*)w;              w += (size_t)N * D * 4;
  float* hA     = (float*)w;              w += (size_t)N * D * 4;
  float* hB     = (float*)w;              w += (size_t)N * D * 4;  // total ~86 MB

  // ---- graph-structure build (once per call) ----
  hipMemsetAsync(deg, 0, 2 * N * sizeof(float), stream);  // deg + counts adjacent
  deg_count_kernel<<<(E + 255) / 256, 256, 0, stream>>>(ew, dst, deg, counts);
  dinv_kernel<<<(N + 255) / 256, 256, 0, stream>>>(deg, dinv);
  coef_kernel<<<(E + 255) / 256, 256, 0, stream>>>(ew, src, dst, dinv, coef);
  scan_reduce_kernel<<<NB, 256, 0, stream>>>(counts, bsum);
  scan_bsum_kernel<<<1, 256, 0, stream>>>(bsum);
  scan_apply_kernel<<<NB, 256, 0, stream>>>(counts, bsum, offs, cursor);
  fill_kernel<<<(E + 255) / 256, 256, 0, stream>>>(src, dst, coef, cursor, csr);

  const int GG = (N + 31) / 32;   // 1563 gemm blocks
  const int AG = N * 32 / 256;    // 6250 agg blocks (exact)

  // layer 1: x -> hA
  gemm_kernel<<<GG, 256, 0, stream>>>(x, W1, nullptr, xw, 0);
  agg_kernel<<<AG, 256, 0, stream>>>(xw, csr, offs, dinv, b1, hA);
  // layer 2: hA -> hB
  gemm_kernel<<<GG, 256, 0, stream>>>(hA, W2, nullptr, xw, 0);
  agg_kernel<<<AG, 256, 0, stream>>>(xw, csr, offs, dinv, b2, hB);
  // layer 3: hB -> hA
  gemm_kernel<<<GG, 256, 0, stream>>>(hB, W3, nullptr, xw, 0);
  agg_kernel<<<AG, 256, 0, stream>>>(xw, csr, offs, dinv, b3, hA);
  // dense head layer: hB = relu(hA @ Wh + bh)
  gemm_kernel<<<GG, 256, 0, stream>>>(hA, Wh, bh, hB, 1);
  // heads -> d_out[0..2T)
  heads_kernel<<<2 * T, 64, 0, stream>>>(hB, ace, h2, Wace, bace, Wh2, bh2, (float*)d_out);
}

// Round 4
// 443.976 us; speedup vs baseline: 7.8210x; 1.1096x over previous
//
#include <hip/hip_runtime.h>
#include <math.h>

constexpr int N = 50000;   // nodes
constexpr int E = 640000;  // edges
constexpr int D = 128;     // dim == hidden
constexpr int T = 100;     // targets per head
constexpr int NB = (N + 255) / 256;  // 196 scan blocks

typedef __attribute__((ext_vector_type(8))) short short8;   // 8 bf16 in 4 VGPRs
typedef __attribute__((ext_vector_type(4))) float f32x4;    // MFMA accumulator

// ---------------- bf16 split helpers (RNE) ----------------

__device__ inline unsigned short bf16_rne(float f) {
  unsigned int u = __float_as_uint(f);
  u += 0x7fff + ((u >> 16) & 1);
  return (unsigned short)(u >> 16);
}
__device__ inline float bf16_f32(unsigned short h) {
  return __uint_as_float((unsigned int)h << 16);
}

// ---------------- fused degree+count histogram: ONE 64-bit atomic per edge ----------------
// high 32 bits: ew in 8.24 fixed point (ew in [0,1), sum < 2^30); low 32: count.

__global__ void deg_count_kernel(const float* __restrict__ ew, const int* __restrict__ dst,
                                 unsigned long long* __restrict__ degcnt) {
  int e = blockIdx.x * 256 + threadIdx.x;
  if (e < E) {
    unsigned int fx = (unsigned int)__float2uint_rn(ew[e] * 16777216.0f);
    atomicAdd(&degcnt[dst[e]], ((unsigned long long)fx << 32) | 1ull);
  }
}

// ---------------- scan phase 1 (+ dinv computation folded in) ----------------

__global__ __launch_bounds__(256) void scan_reduce_kernel(const uint2* __restrict__ degcnt,
                                                          int* __restrict__ bsum,
                                                          float* __restrict__ dinv) {
  __shared__ int part[256];
  int t = threadIdx.x;
  int i = blockIdx.x * 256 + t;
  int c = 0;
  if (i < N) {
    uint2 p = degcnt[i];                      // .x = count (low word), .y = fixed deg
    c = (int)p.x;
    float d = (float)p.y * (1.0f / 16777216.0f) + 1.0f;  // +1 self-loop
    dinv[i] = 1.0f / sqrtf(d);
  }
  part[t] = c;
  __syncthreads();
#pragma unroll
  for (int off = 128; off; off >>= 1) {
    if (t < off) part[t] += part[t + off];
    __syncthreads();
  }
  if (t == 0) bsum[blockIdx.x] = part[0];
}

__global__ __launch_bounds__(256) void scan_bsum_kernel(int* __restrict__ bsum) {
  __shared__ int part[256];
  int t = threadIdx.x;
  int v = (t < NB) ? bsum[t] : 0;
  part[t] = v;
  __syncthreads();
#pragma unroll
  for (int off = 1; off < 256; off <<= 1) {
    int u = (t >= off) ? part[t - off] : 0;
    __syncthreads();
    part[t] += u;
    __syncthreads();
  }
  if (t < NB) bsum[t] = part[t] - v;  // exclusive
}

__global__ __launch_bounds__(256) void scan_apply_kernel(const uint2* __restrict__ degcnt,
                                                         const int* __restrict__ bsum,
                                                         int* __restrict__ offs,
                                                         int* __restrict__ cursor) {
  __shared__ int part[256];
  int t = threadIdx.x;
  int i = blockIdx.x * 256 + t;
  int c = (i < N) ? (int)degcnt[i].x : 0;
  part[t] = c;
  __syncthreads();
#pragma unroll
  for (int off = 1; off < 256; off <<= 1) {
    int u = (t >= off) ? part[t - off] : 0;
    __syncthreads();
    part[t] += u;
    __syncthreads();
  }
  if (i < N) {
    int o = bsum[blockIdx.x] + part[t] - c;  // exclusive
    offs[i] = o;
    cursor[i] = o;
  }
  if (i == 0) offs[N] = E;
}

// ---------------- CSR fill with fused coefficient ----------------

__global__ void fill_kernel(const int* __restrict__ src, const int* __restrict__ dst,
                            const float* __restrict__ ew, const float* __restrict__ dinv,
                            int* __restrict__ cursor, int2* __restrict__ csr) {
  int e = blockIdx.x * 256 + threadIdx.x;
  if (e < E) {
    int s = src[e], d = dst[e];
    float c = dinv[s] * ew[e] * dinv[d];
    int pos = atomicAdd(&cursor[d], 1);
    csr[pos] = make_int2(s, __float_as_int(c));
  }
}

// ---------------- W prep: fp32 W[k][n] -> bf16 hi/lo transposed Wt[n][k], 4 layers ----------------
// wt layout: layer*(2*16384) + {hi: [0,16384), lo: [16384, 32768)}

__global__ void wprep_kernel(const float* __restrict__ W0, const float* __restrict__ W1,
                             const float* __restrict__ W2, const float* __restrict__ W3,
                             unsigned short* __restrict__ wt) {
  int idx = blockIdx.x * 256 + threadIdx.x;  // 0..65535
  int layer = idx >> 14;
  int r = idx & 16383;
  int k = r & 127, n = r >> 7;
  const float* W = layer == 0 ? W0 : layer == 1 ? W1 : layer == 2 ? W2 : W3;
  float v = W[k * D + n];
  unsigned short hi = bf16_rne(v);
  unsigned short lo = bf16_rne(v - bf16_f32(hi));
  unsigned short* dstp = wt + layer * 2 * 16384;
  dstp[n * D + k] = hi;
  dstp[16384 + n * D + k] = lo;
}

// ---------------- split-bf16 MFMA GEMM: out[N x 128] = A @ W (+bias+relu) ----------------
// 64 rows/block, 4 waves; wave w: rows 32*(w&1)+[0,32), cols 64*(w>>1)+[0,64).
// A·B = Ahi·Bhi + Alo·Bhi + Ahi·Blo (lo·lo dropped, ~2^-18 relative).
// X converted fp32->bf16 hi/lo during LDS staging. LDS stride 136 (2-way bank alias = free).

__global__ __launch_bounds__(256) void gemm_mfma_kernel(
    const float* __restrict__ A, const unsigned short* __restrict__ Wt,
    const float* __restrict__ bias, float* __restrict__ out, int relu) {
  constexpr int SX = 136;
  __shared__ unsigned short Xhi[64 * SX];
  __shared__ unsigned short Xlo[64 * SX];
  const int tid = threadIdx.x;
  const int row0 = blockIdx.x * 64;
  const float4* __restrict__ A4 = (const float4*)A;

  // stage + split 64x128 fp32 tile
#pragma unroll
  for (int i = 0; i < 8; ++i) {
    int idx = tid + i * 256;           // 0..2047
    int r = idx >> 5, c4 = idx & 31;
    int gr = row0 + r; if (gr >= N) gr = N - 1;
    float4 v = A4[(size_t)gr * 32 + c4];
    ushort4 h, l;
    h.x = bf16_rne(v.x); l.x = bf16_rne(v.x - bf16_f32(h.x));
    h.y = bf16_rne(v.y); l.y = bf16_rne(v.y - bf16_f32(h.y));
    h.z = bf16_rne(v.z); l.z = bf16_rne(v.z - bf16_f32(h.z));
    h.w = bf16_rne(v.w); l.w = bf16_rne(v.w - bf16_f32(h.w));
    *(ushort4*)&Xhi[r * SX + c4 * 4] = h;
    *(ushort4*)&Xlo[r * SX + c4 * 4] = l;
  }
  __syncthreads();

  const int w = tid >> 6, lane = tid & 63;
  const int q = lane >> 4, n16 = lane & 15;
  const int rbase = (w & 1) * 32;
  const int cbase = (w >> 1) * 64;
  f32x4 acc[2][4] = {{{0.f, 0.f, 0.f, 0.f}, {0.f, 0.f, 0.f, 0.f},
                      {0.f, 0.f, 0.f, 0.f}, {0.f, 0.f, 0.f, 0.f}},
                     {{0.f, 0.f, 0.f, 0.f}, {0.f, 0.f, 0.f, 0.f},
                      {0.f, 0.f, 0.f, 0.f}, {0.f, 0.f, 0.f, 0.f}}};

#pragma unroll
  for (int kc = 0; kc < 4; ++kc) {
    short8 ah[2], al[2];
#pragma unroll
    for (int rt = 0; rt < 2; ++rt) {
      int m = rbase + rt * 16 + n16;
      ah[rt] = *(const short8*)&Xhi[m * SX + kc * 32 + q * 8];
      al[rt] = *(const short8*)&Xlo[m * SX + kc * 32 + q * 8];
    }
#pragma unroll
    for (int ct = 0; ct < 4; ++ct) {
      int n = cbase + ct * 16 + n16;
      short8 bh = *(const short8*)&Wt[n * D + kc * 32 + q * 8];
      short8 bl = *(const short8*)&Wt[16384 + n * D + kc * 32 + q * 8];
#pragma unroll
      for (int rt = 0; rt < 2; ++rt) {
        acc[rt][ct] = __builtin_amdgcn_mfma_f32_16x16x32_bf16(ah[rt], bh, acc[rt][ct], 0, 0, 0);
        acc[rt][ct] = __builtin_amdgcn_mfma_f32_16x16x32_bf16(al[rt], bh, acc[rt][ct], 0, 0, 0);
        acc[rt][ct] = __builtin_amdgcn_mfma_f32_16x16x32_bf16(ah[rt], bl, acc[rt][ct], 0, 0, 0);
      }
    }
  }

  // epilogue: C/D layout col=lane&15, row=(lane>>4)*4+reg
#pragma unroll
  for (int rt = 0; rt < 2; ++rt) {
#pragma unroll
    for (int r = 0; r < 4; ++r) {
      int gr = row0 + rbase + rt * 16 + q * 4 + r;
      if (gr < N) {
#pragma unroll
        for (int ct = 0; ct < 4; ++ct) {
          int col = cbase + ct * 16 + n16;
          float v = acc[rt][ct][r];
          if (bias) v += bias[col];
          if (relu) v = fmaxf(v, 0.f);
          out[(size_t)gr * D + col] = v;
        }
      }
    }
  }
}

// ---------------- pull aggregation: out[n] = relu(dinv[n]^2*xw[n] + b + sum_e coef*xw[src]) ----

__global__ __launch_bounds__(256) void agg_kernel(
    const float* __restrict__ xw, const int2* __restrict__ csr,
    const int* __restrict__ offs, const float* __restrict__ dinv,
    const float* __restrict__ bias, float* __restrict__ out) {
  int g = (blockIdx.x * 256 + threadIdx.x) >> 5;  // node
  if (g >= N) return;
  int lane = threadIdx.x & 31;
  const float4* __restrict__ xw4 = (const float4*)xw;

  float dv = dinv[g];
  float s = dv * dv;
  float4 xv = xw4[g * 32 + lane];
  float4 bv = ((const float4*)bias)[lane];
  float4 acc;
  acc.x = fmaf(s, xv.x, bv.x);
  acc.y = fmaf(s, xv.y, bv.y);
  acc.z = fmaf(s, xv.z, bv.z);
  acc.w = fmaf(s, xv.w, bv.w);

  int e = offs[g], e1 = offs[g + 1];
  for (; e + 2 <= e1; e += 2) {
    int2 p0 = csr[e], p1 = csr[e + 1];
    float c0 = __int_as_float(p0.y), c1 = __int_as_float(p1.y);
    float4 v0 = xw4[p0.x * 32 + lane];
    float4 v1 = xw4[p1.x * 32 + lane];
    acc.x = fmaf(c0, v0.x, acc.x); acc.y = fmaf(c0, v0.y, acc.y);
    acc.z = fmaf(c0, v0.z, acc.z); acc.w = fmaf(c0, v0.w, acc.w);
    acc.x = fmaf(c1, v1.x, acc.x); acc.y = fmaf(c1, v1.y, acc.y);
    acc.z = fmaf(c1, v1.z, acc.z); acc.w = fmaf(c1, v1.w, acc.w);
  }
  if (e < e1) {
    int2 p = csr[e];
    float c = __int_as_float(p.y);
    float4 v = xw4[p.x * 32 + lane];
    acc.x = fmaf(c, v.x, acc.x); acc.y = fmaf(c, v.y, acc.y);
    acc.z = fmaf(c, v.z, acc.z); acc.w = fmaf(c, v.w, acc.w);
  }
  acc.x = fmaxf(acc.x, 0.f); acc.y = fmaxf(acc.y, 0.f);
  acc.z = fmaxf(acc.z, 0.f); acc.w = fmaxf(acc.w, 0.f);
  ((float4*)out)[g * 32 + lane] = acc;
}

// ---------------- heads ----------------

__global__ void heads_kernel(const float* __restrict__ h,
                             const int* __restrict__ ace_idx, const int* __restrict__ h2_idx,
                             const float* __restrict__ Wace, const float* __restrict__ bace,
                             const float* __restrict__ Wh2, const float* __restrict__ bh2,
                             float* __restrict__ out) {
  int t = blockIdx.x;
  int lane = threadIdx.x;
  int node; const float* w; float b;
  if (t < T) { node = ace_idx[t];     w = Wace; b = bace[0]; }
  else       { node = h2_idx[t - T];  w = Wh2;  b = bh2[0]; }
  const float* hr = h + node * D;
  float v = hr[lane] * w[lane] + hr[lane + 64] * w[lane + 64];
#pragma unroll
  for (int off = 32; off; off >>= 1) v += __shfl_down(v, off, 64);
  if (lane == 0) out[t] = v + b;
}

// ---------------- launch ----------------

extern "C" void kernel_launch(void* const* d_in, const int* in_sizes, int n_in,
                              void* d_out, int out_size, void* d_ws, size_t ws_size,
                              hipStream_t stream) {
  const float* x    = (const float*)d_in[0];
  const int*   ei   = (const int*)d_in[1];
  const float* ew   = (const float*)d_in[2];
  const int*   ace  = (const int*)d_in[3];
  const int*   h2   = (const int*)d_in[4];
  const float* W1 = (const float*)d_in[5];  const float* b1 = (const float*)d_in[6];
  const float* W2 = (const float*)d_in[7];  const float* b2 = (const float*)d_in[8];
  const float* W3 = (const float*)d_in[9];  const float* b3 = (const float*)d_in[10];
  const float* Wh = (const float*)d_in[11]; const float* bh = (const float*)d_in[12];
  const float* Wace = (const float*)d_in[13]; const float* bace = (const float*)d_in[14];
  const float* Wh2  = (const float*)d_in[15]; const float* bh2  = (const float*)d_in[16];
  const int* src = ei;
  const int* dst = ei + E;

  // workspace layout (16B-aligned blocks)
  char* w = (char*)d_ws;
  unsigned long long* degcnt = (unsigned long long*)w;  w += (size_t)N * 8;  // zeroed
  float* dinv   = (float*)w;              w += N * 4;
  int*   offs   = (int*)w;                w += (N + 4) * 4;
  int*   cursor = (int*)w;                w += N * 4;
  int*   bsum   = (int*)w;                w += 256 * 4;
  unsigned short* wt = (unsigned short*)w; w += 4 * 2 * 16384 * 2;  // 4 layers hi/lo bf16
  int2*  csr    = (int2*)w;               w += (size_t)E * 8;
  float* xw     = (float*)w;              w += (size_t)N * D * 4;
  float* hA     = (float*)w;              w += (size_t)N * D * 4;
  float* hB     = (float*)w;              w += (size_t)N * D * 4;

  // ---- graph build + W prep ----
  hipMemsetAsync(degcnt, 0, (size_t)N * 8, stream);
  deg_count_kernel<<<(E + 255) / 256, 256, 0, stream>>>(ew, dst, degcnt);
  scan_reduce_kernel<<<NB, 256, 0, stream>>>((const uint2*)degcnt, bsum, dinv);
  scan_bsum_kernel<<<1, 256, 0, stream>>>(bsum);
  scan_apply_kernel<<<NB, 256, 0, stream>>>((const uint2*)degcnt, bsum, offs, cursor);
  fill_kernel<<<(E + 255) / 256, 256, 0, stream>>>(src, dst, ew, dinv, cursor, csr);
  wprep_kernel<<<256, 256, 0, stream>>>(W1, W2, W3, Wh, wt);

  const int GB = (N + 63) / 64;   // 782 gemm blocks
  const int AG = N * 32 / 256;    // 6250 agg blocks

  // layer 1: x -> hA
  gemm_mfma_kernel<<<GB, 256, 0, stream>>>(x, wt + 0 * 32768, nullptr, xw, 0);
  agg_kernel<<<AG, 256, 0, stream>>>(xw, csr, offs, dinv, b1, hA);
  // layer 2: hA -> hB
  gemm_mfma_kernel<<<GB, 256, 0, stream>>>(hA, wt + 1 * 32768, nullptr, xw, 0);
  agg_kernel<<<AG, 256, 0, stream>>>(xw, csr, offs, dinv, b2, hB);
  // layer 3: hB -> hA
  gemm_mfma_kernel<<<GB, 256, 0, stream>>>(hB, wt + 2 * 32768, nullptr, xw, 0);
  agg_kernel<<<AG, 256, 0, stream>>>(xw, csr, offs, dinv, b3, hA);
  // dense head layer: hB = relu(hA @ Wh + bh)
  gemm_mfma_kernel<<<GB, 256, 0, stream>>>(hA, wt + 3 * 32768, bh, hB, 1);
  // heads
  heads_kernel<<<2 * T, 64, 0, stream>>>(hB, ace, h2, Wace, bace, Wh2, bh2, (float*)d_out);
}

// Round 5
// 381.107 us; speedup vs baseline: 9.1112x; 1.1650x over previous
//
#include <hip/hip_runtime.h>
#include <math.h>

constexpr int N = 50000;   // nodes
constexpr int E = 640000;  // edges
constexpr int D = 128;     // dim == hidden
constexpr int T = 100;     // targets per head
constexpr int NB = (N + 255) / 256;  // 196 scan blocks

typedef __attribute__((ext_vector_type(8))) short short8;            // 8 bf16 in 4 VGPRs
typedef __attribute__((ext_vector_type(8))) unsigned short ushort8v; // 8 bf16 payload
typedef __attribute__((ext_vector_type(4))) float f32x4;             // MFMA accumulator

// ---------------- bf16 helpers (RNE) ----------------

__device__ inline unsigned short bf16_rne(float f) {
  unsigned int u = __float_as_uint(f);
  u += 0x7fff + ((u >> 16) & 1);
  return (unsigned short)(u >> 16);
}
__device__ inline float bf16_f32(unsigned short h) {
  return __uint_as_float((unsigned int)h << 16);
}

// ---------------- fused degree+count histogram: ONE 64-bit atomic per edge ----------------
// high 32 bits: ew in 8.24 fixed point (ew in [0,1), sum < 2^30); low 32: count.

__global__ void deg_count_kernel(const float* __restrict__ ew, const int* __restrict__ dst,
                                 unsigned long long* __restrict__ degcnt) {
  int e = blockIdx.x * 256 + threadIdx.x;
  if (e < E) {
    unsigned int fx = (unsigned int)__float2uint_rn(ew[e] * 16777216.0f);
    atomicAdd(&degcnt[dst[e]], ((unsigned long long)fx << 32) | 1ull);
  }
}

// ---------------- scan phase 1 (+ dinv computation folded in) ----------------

__global__ __launch_bounds__(256) void scan_reduce_kernel(const uint2* __restrict__ degcnt,
                                                          int* __restrict__ bsum,
                                                          float* __restrict__ dinv) {
  __shared__ int part[256];
  int t = threadIdx.x;
  int i = blockIdx.x * 256 + t;
  int c = 0;
  if (i < N) {
    uint2 p = degcnt[i];                      // .x = count (low word), .y = fixed deg
    c = (int)p.x;
    float d = (float)p.y * (1.0f / 16777216.0f) + 1.0f;  // +1 self-loop
    dinv[i] = 1.0f / sqrtf(d);
  }
  part[t] = c;
  __syncthreads();
#pragma unroll
  for (int off = 128; off; off >>= 1) {
    if (t < off) part[t] += part[t + off];
    __syncthreads();
  }
  if (t == 0) bsum[blockIdx.x] = part[0];
}

__global__ __launch_bounds__(256) void scan_bsum_kernel(int* __restrict__ bsum) {
  __shared__ int part[256];
  int t = threadIdx.x;
  int v = (t < NB) ? bsum[t] : 0;
  part[t] = v;
  __syncthreads();
#pragma unroll
  for (int off = 1; off < 256; off <<= 1) {
    int u = (t >= off) ? part[t - off] : 0;
    __syncthreads();
    part[t] += u;
    __syncthreads();
  }
  if (t < NB) bsum[t] = part[t] - v;  // exclusive
}

__global__ __launch_bounds__(256) void scan_apply_kernel(const uint2* __restrict__ degcnt,
                                                         const int* __restrict__ bsum,
                                                         int* __restrict__ offs,
                                                         int* __restrict__ cursor) {
  __shared__ int part[256];
  int t = threadIdx.x;
  int i = blockIdx.x * 256 + t;
  int c = (i < N) ? (int)degcnt[i].x : 0;
  part[t] = c;
  __syncthreads();
#pragma unroll
  for (int off = 1; off < 256; off <<= 1) {
    int u = (t >= off) ? part[t - off] : 0;
    __syncthreads();
    part[t] += u;
    __syncthreads();
  }
  if (i < N) {
    int o = bsum[blockIdx.x] + part[t] - c;  // exclusive
    offs[i] = o;
    cursor[i] = o;
  }
  if (i == 0) offs[N] = E;
}

// ---------------- CSR fill with fused coefficient ----------------

__global__ void fill_kernel(const int* __restrict__ src, const int* __restrict__ dst,
                            const float* __restrict__ ew, const float* __restrict__ dinv,
                            int* __restrict__ cursor, int2* __restrict__ csr) {
  int e = blockIdx.x * 256 + threadIdx.x;
  if (e < E) {
    int s = src[e], d = dst[e];
    float c = dinv[s] * ew[e] * dinv[d];
    int pos = atomicAdd(&cursor[d], 1);
    csr[pos] = make_int2(s, __float_as_int(c));
  }
}

// ---------------- W prep: fp32 W[k][n] -> bf16 hi/lo transposed Wt[n][k], 4 layers ----------------

__global__ void wprep_kernel(const float* __restrict__ W0, const float* __restrict__ W1,
                             const float* __restrict__ W2, const float* __restrict__ W3,
                             unsigned short* __restrict__ wt) {
  int idx = blockIdx.x * 256 + threadIdx.x;  // 0..65535
  int layer = idx >> 14;
  int r = idx & 16383;
  int k = r & 127, n = r >> 7;
  const float* W = layer == 0 ? W0 : layer == 1 ? W1 : layer == 2 ? W2 : W3;
  float v = W[k * D + n];
  unsigned short hi = bf16_rne(v);
  unsigned short lo = bf16_rne(v - bf16_f32(hi));
  unsigned short* dstp = wt + layer * 2 * 16384;
  dstp[n * D + k] = hi;
  dstp[16384 + n * D + k] = lo;
}

// ---------------- split-bf16 MFMA GEMM: out[N x 128] = A @ W (+bias+relu) ----------------
// 64 rows/block, 4 waves. A·B = Ahi·Bhi + Alo·Bhi + Ahi·Blo.
// out_bf16=1: write bf16 (layers 1-3, feeds agg); else fp32.

__global__ __launch_bounds__(256) void gemm_mfma_kernel(
    const float* __restrict__ A, const unsigned short* __restrict__ Wt,
    const float* __restrict__ bias, void* __restrict__ out, int relu, int out_bf16) {
  constexpr int SX = 136;
  __shared__ unsigned short Xhi[64 * SX];
  __shared__ unsigned short Xlo[64 * SX];
  const int tid = threadIdx.x;
  const int row0 = blockIdx.x * 64;
  const float4* __restrict__ A4 = (const float4*)A;

  // stage + split 64x128 fp32 tile
#pragma unroll
  for (int i = 0; i < 8; ++i) {
    int idx = tid + i * 256;           // 0..2047
    int r = idx >> 5, c4 = idx & 31;
    int gr = row0 + r; if (gr >= N) gr = N - 1;
    float4 v = A4[(size_t)gr * 32 + c4];
    ushort4 h, l;
    h.x = bf16_rne(v.x); l.x = bf16_rne(v.x - bf16_f32(h.x));
    h.y = bf16_rne(v.y); l.y = bf16_rne(v.y - bf16_f32(h.y));
    h.z = bf16_rne(v.z); l.z = bf16_rne(v.z - bf16_f32(h.z));
    h.w = bf16_rne(v.w); l.w = bf16_rne(v.w - bf16_f32(h.w));
    *(ushort4*)&Xhi[r * SX + c4 * 4] = h;
    *(ushort4*)&Xlo[r * SX + c4 * 4] = l;
  }
  __syncthreads();

  const int w = tid >> 6, lane = tid & 63;
  const int q = lane >> 4, n16 = lane & 15;
  const int rbase = (w & 1) * 32;
  const int cbase = (w >> 1) * 64;
  f32x4 acc[2][4] = {{{0.f, 0.f, 0.f, 0.f}, {0.f, 0.f, 0.f, 0.f},
                      {0.f, 0.f, 0.f, 0.f}, {0.f, 0.f, 0.f, 0.f}},
                     {{0.f, 0.f, 0.f, 0.f}, {0.f, 0.f, 0.f, 0.f},
                      {0.f, 0.f, 0.f, 0.f}, {0.f, 0.f, 0.f, 0.f}}};

#pragma unroll
  for (int kc = 0; kc < 4; ++kc) {
    short8 ah[2], al[2];
#pragma unroll
    for (int rt = 0; rt < 2; ++rt) {
      int m = rbase + rt * 16 + n16;
      ah[rt] = *(const short8*)&Xhi[m * SX + kc * 32 + q * 8];
      al[rt] = *(const short8*)&Xlo[m * SX + kc * 32 + q * 8];
    }
#pragma unroll
    for (int ct = 0; ct < 4; ++ct) {
      int n = cbase + ct * 16 + n16;
      short8 bh = *(const short8*)&Wt[n * D + kc * 32 + q * 8];
      short8 bl = *(const short8*)&Wt[16384 + n * D + kc * 32 + q * 8];
#pragma unroll
      for (int rt = 0; rt < 2; ++rt) {
        acc[rt][ct] = __builtin_amdgcn_mfma_f32_16x16x32_bf16(ah[rt], bh, acc[rt][ct], 0, 0, 0);
        acc[rt][ct] = __builtin_amdgcn_mfma_f32_16x16x32_bf16(al[rt], bh, acc[rt][ct], 0, 0, 0);
        acc[rt][ct] = __builtin_amdgcn_mfma_f32_16x16x32_bf16(ah[rt], bl, acc[rt][ct], 0, 0, 0);
      }
    }
  }

  // epilogue: C/D layout col=lane&15, row=(lane>>4)*4+reg
#pragma unroll
  for (int rt = 0; rt < 2; ++rt) {
#pragma unroll
    for (int r = 0; r < 4; ++r) {
      int gr = row0 + rbase + rt * 16 + q * 4 + r;
      if (gr < N) {
#pragma unroll
        for (int ct = 0; ct < 4; ++ct) {
          int col = cbase + ct * 16 + n16;
          float v = acc[rt][ct][r];
          if (bias) v += bias[col];
          if (relu) v = fmaxf(v, 0.f);
          if (out_bf16) ((unsigned short*)out)[(size_t)gr * D + col] = bf16_rne(v);
          else          ((float*)out)[(size_t)gr * D + col] = v;
        }
      }
    }
  }
}

// ---------------- pull aggregation over bf16 xw ----------------
// out[n] = relu(dinv[n]^2*xw[n] + b + sum_e coef*xw[src]), fp32 accumulate, fp32 out.
// 16 lanes per node; each lane owns 8 bf16 (16B load). Wave gathers 4 edge rows per issue.

__global__ __launch_bounds__(256) void agg_kernel(
    const unsigned short* __restrict__ xwb, const int2* __restrict__ csr,
    const int* __restrict__ offs, const float* __restrict__ dinv,
    const float* __restrict__ bias, float* __restrict__ out) {
  int g = (blockIdx.x * 256 + threadIdx.x) >> 4;  // node; 16 nodes/block, 3125 blocks exact
  int lane = threadIdx.x & 15;

  float dv = dinv[g];
  float s = dv * dv;
  ushort8v xv = *(const ushort8v*)&xwb[(size_t)g * D + lane * 8];
  float acc[8];
#pragma unroll
  for (int i = 0; i < 8; ++i)
    acc[i] = fmaf(s, bf16_f32(xv[i]), bias[lane * 8 + i]);

  int e = offs[g], e1 = offs[g + 1];
  for (; e + 2 <= e1; e += 2) {
    int2 p0 = csr[e], p1 = csr[e + 1];
    float c0 = __int_as_float(p0.y), c1 = __int_as_float(p1.y);
    ushort8v v0 = *(const ushort8v*)&xwb[(size_t)p0.x * D + lane * 8];
    ushort8v v1 = *(const ushort8v*)&xwb[(size_t)p1.x * D + lane * 8];
#pragma unroll
    for (int i = 0; i < 8; ++i) {
      acc[i] = fmaf(c0, bf16_f32(v0[i]), acc[i]);
      acc[i] = fmaf(c1, bf16_f32(v1[i]), acc[i]);
    }
  }
  if (e < e1) {
    int2 p = csr[e];
    float c = __int_as_float(p.y);
    ushort8v v = *(const ushort8v*)&xwb[(size_t)p.x * D + lane * 8];
#pragma unroll
    for (int i = 0; i < 8; ++i) acc[i] = fmaf(c, bf16_f32(v[i]), acc[i]);
  }

  float4 o0, o1;
  o0.x = fmaxf(acc[0], 0.f); o0.y = fmaxf(acc[1], 0.f);
  o0.z = fmaxf(acc[2], 0.f); o0.w = fmaxf(acc[3], 0.f);
  o1.x = fmaxf(acc[4], 0.f); o1.y = fmaxf(acc[5], 0.f);
  o1.z = fmaxf(acc[6], 0.f); o1.w = fmaxf(acc[7], 0.f);
  float4* op = (float4*)(out + (size_t)g * D + lane * 8);
  op[0] = o0;
  op[1] = o1;
}

// ---------------- heads ----------------

__global__ void heads_kernel(const float* __restrict__ h,
                             const int* __restrict__ ace_idx, const int* __restrict__ h2_idx,
                             const float* __restrict__ Wace, const float* __restrict__ bace,
                             const float* __restrict__ Wh2, const float* __restrict__ bh2,
                             float* __restrict__ out) {
  int t = blockIdx.x;
  int lane = threadIdx.x;
  int node; const float* w; float b;
  if (t < T) { node = ace_idx[t];     w = Wace; b = bace[0]; }
  else       { node = h2_idx[t - T];  w = Wh2;  b = bh2[0]; }
  const float* hr = h + node * D;
  float v = hr[lane] * w[lane] + hr[lane + 64] * w[lane + 64];
#pragma unroll
  for (int off = 32; off; off >>= 1) v += __shfl_down(v, off, 64);
  if (lane == 0) out[t] = v + b;
}

// ---------------- launch ----------------

extern "C" void kernel_launch(void* const* d_in, const int* in_sizes, int n_in,
                              void* d_out, int out_size, void* d_ws, size_t ws_size,
                              hipStream_t stream) {
  const float* x    = (const float*)d_in[0];
  const int*   ei   = (const int*)d_in[1];
  const float* ew   = (const float*)d_in[2];
  const int*   ace  = (const int*)d_in[3];
  const int*   h2   = (const int*)d_in[4];
  const float* W1 = (const float*)d_in[5];  const float* b1 = (const float*)d_in[6];
  const float* W2 = (const float*)d_in[7];  const float* b2 = (const float*)d_in[8];
  const float* W3 = (const float*)d_in[9];  const float* b3 = (const float*)d_in[10];
  const float* Wh = (const float*)d_in[11]; const float* bh = (const float*)d_in[12];
  const float* Wace = (const float*)d_in[13]; const float* bace = (const float*)d_in[14];
  const float* Wh2  = (const float*)d_in[15]; const float* bh2  = (const float*)d_in[16];
  const int* src = ei;
  const int* dst = ei + E;

  // workspace layout (16B-aligned blocks)
  char* w = (char*)d_ws;
  unsigned long long* degcnt = (unsigned long long*)w;  w += (size_t)N * 8;  // zeroed
  float* dinv   = (float*)w;              w += N * 4;
  int*   offs   = (int*)w;                w += (N + 4) * 4;
  int*   cursor = (int*)w;                w += N * 4;
  int*   bsum   = (int*)w;                w += 256 * 4;
  unsigned short* wt = (unsigned short*)w; w += 4 * 2 * 16384 * 2;  // 4 layers hi/lo bf16
  int2*  csr    = (int2*)w;               w += (size_t)E * 8;
  unsigned short* xwb = (unsigned short*)w; w += (size_t)N * D * 2;  // bf16 GEMM out
  float* hA     = (float*)w;              w += (size_t)N * D * 4;
  float* hB     = (float*)w;              w += (size_t)N * D * 4;

  // ---- graph build + W prep ----
  hipMemsetAsync(degcnt, 0, (size_t)N * 8, stream);
  deg_count_kernel<<<(E + 255) / 256, 256, 0, stream>>>(ew, dst, degcnt);
  scan_reduce_kernel<<<NB, 256, 0, stream>>>((const uint2*)degcnt, bsum, dinv);
  scan_bsum_kernel<<<1, 256, 0, stream>>>(bsum);
  scan_apply_kernel<<<NB, 256, 0, stream>>>((const uint2*)degcnt, bsum, offs, cursor);
  fill_kernel<<<(E + 255) / 256, 256, 0, stream>>>(src, dst, ew, dinv, cursor, csr);
  wprep_kernel<<<256, 256, 0, stream>>>(W1, W2, W3, Wh, wt);

  const int GB = (N + 63) / 64;   // 782 gemm blocks
  const int AG = N * 16 / 256;    // 3125 agg blocks (exact)

  // layer 1: x -> hA
  gemm_mfma_kernel<<<GB, 256, 0, stream>>>(x, wt + 0 * 32768, nullptr, xwb, 0, 1);
  agg_kernel<<<AG, 256, 0, stream>>>(xwb, csr, offs, dinv, b1, hA);
  // layer 2: hA -> hB
  gemm_mfma_kernel<<<GB, 256, 0, stream>>>(hA, wt + 1 * 32768, nullptr, xwb, 0, 1);
  agg_kernel<<<AG, 256, 0, stream>>>(xwb, csr, offs, dinv, b2, hB);
  // layer 3: hB -> hA
  gemm_mfma_kernel<<<GB, 256, 0, stream>>>(hB, wt + 2 * 32768, nullptr, xwb, 0, 1);
  agg_kernel<<<AG, 256, 0, stream>>>(xwb, csr, offs, dinv, b3, hA);
  // dense head layer: hB = relu(hA @ Wh + bh), fp32 out
  gemm_mfma_kernel<<<GB, 256, 0, stream>>>(hA, wt + 3 * 32768, bh, hB, 1, 0);
  // heads
  heads_kernel<<<2 * T, 64, 0, stream>>>(hB, ace, h2, Wace, bace, Wh2, bh2, (float*)d_out);
}